// Round 19
// baseline (1912.757 us; speedup 1.0000x reference)
//
#include <hip/hip_runtime.h>
#include <hip/hip_fp16.h>

#define B 32
#define S 512
#define E 512
#define H 512
#define NH 8
#define HD 64
#define POISON 0x7FC0DEADu

typedef _Float16 h16x8 __attribute__((ext_vector_type(8)));
typedef _Float16 h16x4 __attribute__((ext_vector_type(4)));
typedef _Float16 h16x2 __attribute__((ext_vector_type(2)));
typedef float f32x4 __attribute__((ext_vector_type(4)));

#if __has_builtin(__builtin_amdgcn_fdot2)
__device__ __forceinline__ float dot2f(h16x2 a, h16x2 b, float c) {
    return __builtin_amdgcn_fdot2(a, b, c, false);
}
#else
__device__ __forceinline__ float dot2f(h16x2 a, h16x2 b, float c) {
    return c + (float)a[0] * (float)b[0] + (float)a[1] * (float)b[1];
}
#endif

__device__ __forceinline__ h16x2 pr(h16x8 v, int q) {
    h16x2 r; r[0] = v[2 * q]; r[1] = v[2 * q + 1]; return r;
}

// ---------------- fp32 -> fp16 cast (vectorized, grid-stride) ----------------
__global__ __launch_bounds__(256) void cast_h(const float* __restrict__ src,
                                              _Float16* __restrict__ dst, int n4) {
    int i = blockIdx.x * 256 + threadIdx.x;
    const int stride = gridDim.x * 256;
    for (; i < n4; i += stride) {
        float4 v = ((const float4*)src)[i];
        h16x4 o;
        o[0] = (_Float16)v.x; o[1] = (_Float16)v.y;
        o[2] = (_Float16)v.z; o[3] = (_Float16)v.w;
        ((h16x4*)dst)[i] = o;
    }
}

// ---------------- MFMA GEMM: C[M,N] = A[M,K] @ W[N,K]^T + bias ----------------
// OMODE 1: f16 row-major. 2: f16 scattered to Vt[(b*8+h)*64+d][s].
// 3: f32 time-major scatter row r=b*512+s -> C[(s*32+b)*N+c].
template <int OMODE>
__global__ __launch_bounds__(256) void gemm_mfma(const _Float16* __restrict__ A,
                                                 const _Float16* __restrict__ W,
                                                 const float* __restrict__ bias,
                                                 void* __restrict__ Cout,
                                                 int M, int N, int K) {
    __shared__ __align__(16) _Float16 Als[128 * 32];
    __shared__ __align__(16) _Float16 Bls[128 * 32];
    const int tid = threadIdx.x;
    const int m0 = blockIdx.y * 128;
    const int n0 = blockIdx.x * 128;
    const int lane = tid & 63;
    const int w = tid >> 6;
    const int wm = w >> 1, wn = w & 1;
    f32x4 acc[4][4] = {};

    const int srow = tid >> 1;
    const int shalf = tid & 1;
    const _Float16* Ag = A + (size_t)(m0 + srow) * K + shalf * 16;
    const _Float16* Wg = W + (size_t)(n0 + srow) * K + shalf * 16;

    for (int k0 = 0; k0 < K; k0 += 32) {
        h16x8 a0 = *(const h16x8*)(Ag + k0);
        h16x8 a1 = *(const h16x8*)(Ag + k0 + 8);
        h16x8 b0 = *(const h16x8*)(Wg + k0);
        h16x8 b1 = *(const h16x8*)(Wg + k0 + 8);
        __syncthreads();
        *(h16x8*)&Als[srow * 32 + shalf * 16] = a0;
        *(h16x8*)&Als[srow * 32 + shalf * 16 + 8] = a1;
        *(h16x8*)&Bls[srow * 32 + shalf * 16] = b0;
        *(h16x8*)&Bls[srow * 32 + shalf * 16 + 8] = b1;
        __syncthreads();
        h16x8 af[4], bf[4];
#pragma unroll
        for (int mt = 0; mt < 4; ++mt)
            af[mt] = *(const h16x8*)&Als[(wm * 64 + mt * 16 + (lane & 15)) * 32 + (lane >> 4) * 8];
#pragma unroll
        for (int nt = 0; nt < 4; ++nt)
            bf[nt] = *(const h16x8*)&Bls[(wn * 64 + nt * 16 + (lane & 15)) * 32 + (lane >> 4) * 8];
#pragma unroll
        for (int mt = 0; mt < 4; ++mt)
#pragma unroll
            for (int nt = 0; nt < 4; ++nt)
                acc[mt][nt] = __builtin_amdgcn_mfma_f32_16x16x32_f16(af[mt], bf[nt], acc[mt][nt], 0, 0, 0);
    }

    float* Cf = (float*)Cout;
    _Float16* Ch = (_Float16*)Cout;
    const int colb = n0 + wn * 64 + (lane & 15);
    const int rowb = m0 + wm * 64 + ((lane >> 4) << 2);
#pragma unroll
    for (int mt = 0; mt < 4; ++mt) {
#pragma unroll
        for (int nt = 0; nt < 4; ++nt) {
            const int c = colb + nt * 16;
            const float bv = bias[c];
            if (OMODE == 2) {
                const int R0 = rowb + mt * 16;
                const int bb = R0 >> 9, s = R0 & 511, hh = c >> 6, d = c & 63;
                h16x4 pk;
#pragma unroll
                for (int j = 0; j < 4; ++j) pk[j] = (_Float16)(acc[mt][nt][j] + bv);
                *(h16x4*)&Ch[((size_t)(bb * 8 + hh) * 64 + d) * 512 + s] = pk;
            } else {
#pragma unroll
                for (int j = 0; j < 4; ++j) {
                    const int R = rowb + mt * 16 + j;
                    const float v = acc[mt][nt][j] + bv;
                    if (OMODE == 3) Cf[((size_t)(R & 511) * 32 + (R >> 9)) * N + c] = v;
                    else Ch[(size_t)R * N + c] = (_Float16)v;
                }
            }
        }
    }
}

// ---------------- MFMA flash attention: per (b, h, 64-row q-tile) ----------------
__global__ __launch_bounds__(256) void attn_mfma(_Float16* __restrict__ Qb,
                                                 const _Float16* __restrict__ Kb,
                                                 const _Float16* __restrict__ Vt) {
    __shared__ __align__(16) _Float16 Qs[64 * 72];
    __shared__ __align__(16) _Float16 Ks[64 * 72];
    __shared__ __align__(16) _Float16 Vs[64 * 72];
    __shared__ __align__(16) _Float16 Ps[4 * 16 * 72];
    const int tid = threadIdx.x;
    const int lane = tid & 63;
    const int w = tid >> 6;
    const int qt = blockIdx.x & 7;
    const int h = (blockIdx.x >> 3) & 7;
    const int b = blockIdx.x >> 6;
    const size_t qrow0 = (size_t)b * 512 + qt * 64;
    const int col0 = h * 64;

    {
        const int r = tid >> 2;
        const int c0 = (tid & 3) << 4;
        const _Float16* gq = &Qb[(qrow0 + r) * 512 + col0 + c0];
        *(h16x8*)&Qs[r * 72 + c0] = *(const h16x8*)(gq);
        *(h16x8*)&Qs[r * 72 + c0 + 8] = *(const h16x8*)(gq + 8);
    }
    __syncthreads();
    h16x8 aq[2];
#pragma unroll
    for (int ks = 0; ks < 2; ++ks)
        aq[ks] = *(const h16x8*)&Qs[(w * 16 + (lane & 15)) * 72 + ks * 32 + (lane >> 4) * 8];

    float m[4] = {-1e30f, -1e30f, -1e30f, -1e30f};
    float l[4] = {0.f, 0.f, 0.f, 0.f};
    f32x4 acco[4] = {};

    for (int kt = 0; kt < 8; ++kt) {
        __syncthreads();
        {
            const int r = tid >> 2;
            const int c0 = (tid & 3) << 4;
            const _Float16* gk = &Kb[((size_t)b * 512 + kt * 64 + r) * 512 + col0 + c0];
            *(h16x8*)&Ks[r * 72 + c0] = *(const h16x8*)(gk);
            *(h16x8*)&Ks[r * 72 + c0 + 8] = *(const h16x8*)(gk + 8);
            const _Float16* gv = &Vt[((size_t)(b * 8 + h) * 64 + r) * 512 + kt * 64 + c0];
            *(h16x8*)&Vs[r * 72 + c0] = *(const h16x8*)(gv);
            *(h16x8*)&Vs[r * 72 + c0 + 8] = *(const h16x8*)(gv + 8);
        }
        __syncthreads();
        f32x4 accs[4] = {};
#pragma unroll
        for (int nt = 0; nt < 4; ++nt) {
#pragma unroll
            for (int ks = 0; ks < 2; ++ks) {
                h16x8 bk = *(const h16x8*)&Ks[(nt * 16 + (lane & 15)) * 72 + ks * 32 + (lane >> 4) * 8];
                accs[nt] = __builtin_amdgcn_mfma_f32_16x16x32_f16(aq[ks], bk, accs[nt], 0, 0, 0);
            }
        }
#pragma unroll
        for (int j = 0; j < 4; ++j) {
            float v = fmaxf(fmaxf(accs[0][j], accs[1][j]), fmaxf(accs[2][j], accs[3][j]));
#pragma unroll
            for (int o = 1; o < 16; o <<= 1) v = fmaxf(v, __shfl_xor(v, o, 64));
            const float mn = fmaxf(m[j], v);
            const float scl = __expf(0.125f * (m[j] - mn));
            m[j] = mn;
            l[j] *= scl;
#pragma unroll
            for (int nt2 = 0; nt2 < 4; ++nt2) acco[nt2][j] *= scl;
            float ps = 0.f;
            const int prow = ((lane >> 4) << 2) + j;
#pragma unroll
            for (int nt = 0; nt < 4; ++nt) {
                const float p = __expf(0.125f * (accs[nt][j] - mn));
                ps += p;
                Ps[w * 16 * 72 + prow * 72 + nt * 16 + (lane & 15)] = (_Float16)p;
            }
#pragma unroll
            for (int o = 1; o < 16; o <<= 1) ps += __shfl_xor(ps, o, 64);
            l[j] += ps;
        }
        __syncthreads();
#pragma unroll
        for (int ks2 = 0; ks2 < 2; ++ks2) {
            h16x8 pa = *(const h16x8*)&Ps[w * 16 * 72 + (lane & 15) * 72 + ks2 * 32 + (lane >> 4) * 8];
#pragma unroll
            for (int nt2 = 0; nt2 < 4; ++nt2) {
                h16x8 bv = *(const h16x8*)&Vs[(nt2 * 16 + (lane & 15)) * 72 + ks2 * 32 + (lane >> 4) * 8];
                acco[nt2] = __builtin_amdgcn_mfma_f32_16x16x32_f16(pa, bv, acco[nt2], 0, 0, 0);
            }
        }
    }
#pragma unroll
    for (int j = 0; j < 4; ++j) {
        const float inv = 1.0f / l[j];
        const size_t r = qrow0 + w * 16 + ((lane >> 4) << 2) + j;
#pragma unroll
        for (int nt2 = 0; nt2 < 4; ++nt2)
            Qb[r * 512 + col0 + nt2 * 16 + (lane & 15)] = (_Float16)(acco[nt2][j] * inv);
    }
}

// ---------------- poison fill ----------------
__global__ __launch_bounds__(256) void fill_poison(uint4* __restrict__ p, int n) {
    const uint4 v = {POISON, POISON, POISON, POISON};
    int i = blockIdx.x * 256 + threadIdx.x;
    const int st = gridDim.x * 256;
    for (; i < n; i += st) p[i] = v;
}

__device__ __forceinline__ unsigned long long poll2(const unsigned* p) {
    unsigned long long v = __hip_atomic_load((const unsigned long long*)p,
                                             __ATOMIC_RELAXED, __HIP_MEMORY_SCOPE_AGENT);
    while ((unsigned)v == POISON || (unsigned)(v >> 32) == POISON) {
        __builtin_amdgcn_s_sleep(1);
        v = __hip_atomic_load((const unsigned long long*)p,
                              __ATOMIC_RELAXED, __HIP_MEMORY_SCOPE_AGENT);
    }
    return v;
}

// ---- fused 2-layer RNN, round-12 mechanics for BOTH roles (no LDS weights) --------
// 512 blocks: role = bid>>8 (0: layer0, 1: layer1); b = bid&31; sl = (bid>>5)&7.
// All weights stream from L2 as fp16, prefetched before the polls. L1 computes
// pre1 on the fly (Wih1 . h0[t] + bih1), with its two polls issued back-to-back so
// their latencies overlap. Sync: per-thread u64 poison-poll only; no fences.
__global__ __launch_bounds__(256) void rnn_fused2L(const float* __restrict__ pre0,
                                                   const _Float16* __restrict__ Whh0h,
                                                   const _Float16* __restrict__ Whh1h,
                                                   const _Float16* __restrict__ Wih1h,
                                                   const float* __restrict__ bhh,
                                                   const float* __restrict__ bih,
                                                   unsigned* __restrict__ h0u,
                                                   unsigned* __restrict__ h1u) {
    __shared__ float hl[512];    // own-layer h(t-1)
    __shared__ float hl0[512];   // role 1 only: h0[t]
    __shared__ float part[64][17];
    const int tid = threadIdx.x;
    const int role = blockIdx.x >> 8;
    const int b = blockIdx.x & 31;
    const int sl = (blockIdx.x >> 5) & 7;
    const int jq = tid & 15, kg = tid >> 4;
    const int jbase = sl * 64, k0 = kg * 32;
    const int j64 = tid & 63;

    const _Float16* Wmy = role ? Whh1h : Whh0h;
    const _Float16* w0p = Wmy + (size_t)(jbase + jq * 4 + 0) * 512 + k0;
    const _Float16* w1p = Wmy + (size_t)(jbase + jq * 4 + 1) * 512 + k0;
    const _Float16* w2p = Wmy + (size_t)(jbase + jq * 4 + 2) * 512 + k0;
    const _Float16* w3p = Wmy + (size_t)(jbase + jq * 4 + 3) * 512 + k0;
    const _Float16* u0p = Wih1h + (size_t)(jbase + jq * 4 + 0) * 512 + k0;
    const _Float16* u1p = Wih1h + (size_t)(jbase + jq * 4 + 1) * 512 + k0;
    const _Float16* u2p = Wih1h + (size_t)(jbase + jq * 4 + 2) * 512 + k0;
    const _Float16* u3p = Wih1h + (size_t)(jbase + jq * 4 + 3) * 512 + k0;
    const float bj = role ? (bih[512 + jbase + j64] + bhh[512 + jbase + j64])
                          : bhh[jbase + j64];
    unsigned* myH = role ? h1u : h0u;

    for (int t = 0; t < S; ++t) {
        // prefetch own-layer Whh fragments (fly during the polls)
        h16x8 w0[4], w1[4], w2[4], w3[4];
#pragma unroll
        for (int c8 = 0; c8 < 4; ++c8) {
            w0[c8] = *(const h16x8*)(w0p + c8 * 8);
            w1[c8] = *(const h16x8*)(w1p + c8 * 8);
            w2[c8] = *(const h16x8*)(w2p + c8 * 8);
            w3[c8] = *(const h16x8*)(w3p + c8 * 8);
        }
        float pv = 0.f;
        h16x8 u0[4], u1[4], u2[4], u3[4];
        if (role == 0) {
            pv = pre0[((size_t)t * 32 + b) * 512 + jbase + j64];
        } else {
#pragma unroll
            for (int c8 = 0; c8 < 4; ++c8) {
                u0[c8] = *(const h16x8*)(u0p + c8 * 8);
                u1[c8] = *(const h16x8*)(u1p + c8 * 8);
                u2[c8] = *(const h16x8*)(u2p + c8 * 8);
                u3[c8] = *(const h16x8*)(u3p + c8 * 8);
            }
        }
        // polls back-to-back (latencies overlap), then one barrier
        if (role == 1) {
            const unsigned long long v0 =
                poll2(h0u + (size_t)t * (B * H) + b * H + tid * 2);
            hl0[tid * 2] = __uint_as_float((unsigned)v0);
            hl0[tid * 2 + 1] = __uint_as_float((unsigned)(v0 >> 32));
        }
        if (t > 0) {
            const unsigned long long v =
                poll2(myH + (size_t)(t - 1) * (B * H) + b * H + tid * 2);
            hl[tid * 2] = __uint_as_float((unsigned)v);
            hl[tid * 2 + 1] = __uint_as_float((unsigned)(v >> 32));
        }
        if (role == 1 || t > 0) __syncthreads();

        float a0 = 0.f, a1 = 0.f, a2 = 0.f, a3 = 0.f;
        if (role == 1) {   // pre1 contribution: Wih1 . h0[t]
            f32x4 hw[8];
#pragma unroll
            for (int c = 0; c < 8; ++c) hw[c] = *(const f32x4*)&hl0[k0 + c * 4];
            h16x2 hp[16];
#pragma unroll
            for (int c = 0; c < 8; ++c) {
                h16x2 p0, p1;
                p0[0] = (_Float16)hw[c][0]; p0[1] = (_Float16)hw[c][1];
                p1[0] = (_Float16)hw[c][2]; p1[1] = (_Float16)hw[c][3];
                hp[2 * c] = p0; hp[2 * c + 1] = p1;
            }
#pragma unroll
            for (int c8 = 0; c8 < 4; ++c8) {
#pragma unroll
                for (int q = 0; q < 4; ++q) {
                    a0 = dot2f(pr(u0[c8], q), hp[c8 * 4 + q], a0);
                    a1 = dot2f(pr(u1[c8], q), hp[c8 * 4 + q], a1);
                    a2 = dot2f(pr(u2[c8], q), hp[c8 * 4 + q], a2);
                    a3 = dot2f(pr(u3[c8], q), hp[c8 * 4 + q], a3);
                }
            }
        }
        if (t > 0) {       // own-layer recurrence: Whh . h(t-1)
            f32x4 hw[8];
#pragma unroll
            for (int c = 0; c < 8; ++c) hw[c] = *(const f32x4*)&hl[k0 + c * 4];
            h16x2 hp[16];
#pragma unroll
            for (int c = 0; c < 8; ++c) {
                h16x2 p0, p1;
                p0[0] = (_Float16)hw[c][0]; p0[1] = (_Float16)hw[c][1];
                p1[0] = (_Float16)hw[c][2]; p1[1] = (_Float16)hw[c][3];
                hp[2 * c] = p0; hp[2 * c + 1] = p1;
            }
#pragma unroll
            for (int c8 = 0; c8 < 4; ++c8) {
#pragma unroll
                for (int q = 0; q < 4; ++q) {
                    a0 = dot2f(pr(w0[c8], q), hp[c8 * 4 + q], a0);
                    a1 = dot2f(pr(w1[c8], q), hp[c8 * 4 + q], a1);
                    a2 = dot2f(pr(w2[c8], q), hp[c8 * 4 + q], a2);
                    a3 = dot2f(pr(w3[c8], q), hp[c8 * 4 + q], a3);
                }
            }
        }
        part[jq * 4 + 0][kg] = a0;
        part[jq * 4 + 1][kg] = a1;
        part[jq * 4 + 2][kg] = a2;
        part[jq * 4 + 3][kg] = a3;
        __syncthreads();   // part ready; hl/hl0 fully consumed
        if (tid < 64) {
            float s2 = 0.f;
#pragma unroll
            for (int i = 0; i < 16; ++i) s2 += part[tid][i];
            s2 += bj + pv;
            s2 = fminf(fmaxf(s2, -15.f), 15.f);
            const float ex = __expf(2.f * s2);
            const float hval = (ex - 1.f) / (ex + 1.f);
            __hip_atomic_store(&myH[(size_t)t * (B * H) + b * H + jbase + tid],
                               __float_as_uint(hval), __ATOMIC_RELAXED,
                               __HIP_MEMORY_SCOPE_AGENT);
        }
        __syncthreads();   // part[] protected before next iteration
    }
}

// ---------------- final FC: out[b] = h1[511][b,:] . Wfc[0,:] + bfc[0] ----------------
__global__ __launch_bounds__(64) void fc_out(const unsigned* __restrict__ hbits,
                                             const float* __restrict__ Wfc,
                                             const float* __restrict__ bfc,
                                             float* __restrict__ out) {
    int b = blockIdx.x;
    int t = threadIdx.x;
    float a = 0.f;
    for (int j = t; j < 512; j += 64) a += __uint_as_float(hbits[b * 512 + j]) * Wfc[j];
#pragma unroll
    for (int o = 32; o; o >>= 1) a += __shfl_down(a, o, 64);
    if (t == 0) out[b] = a + bfc[0];
}

extern "C" void kernel_launch(void* const* d_in, const int* in_sizes, int n_in,
                              void* d_out, int out_size, void* d_ws, size_t ws_size,
                              hipStream_t stream) {
    const float* x   = (const float*)d_in[0];
    const float* Wq  = (const float*)d_in[1];
    const float* bq  = (const float*)d_in[2];
    const float* Wk  = (const float*)d_in[3];
    const float* bk  = (const float*)d_in[4];
    const float* Wv  = (const float*)d_in[5];
    const float* bv  = (const float*)d_in[6];
    const float* Wo  = (const float*)d_in[7];
    const float* bo  = (const float*)d_in[8];
    const float* Wih = (const float*)d_in[9];
    const float* bih = (const float*)d_in[10];
    const float* Whh = (const float*)d_in[11];
    const float* bhh = (const float*)d_in[12];
    const float* Wfc = (const float*)d_in[13];
    const float* bfc = (const float*)d_in[14];
    float* out = (float*)d_out;
    char* base = (char*)d_ws;

    // [0,32M):  x_f16 -> h0 u32 slab
    // [32,48M): Q_f16 -> ctx f16
    // [48,80M): K_f16 / Vt f16 -> h1 u32 slab
    // [80,112M): pre0 f32 [t][b][512]
    // [112,116M): 8 fp16 weight slices
    _Float16* xh   = (_Float16*)(base);
    unsigned* h0u  = (unsigned*)(base);
    _Float16* Qh   = (_Float16*)(base + ((size_t)32 << 20));
    _Float16* Kh   = (_Float16*)(base + ((size_t)48 << 20));
    unsigned* h1u  = (unsigned*)(base + ((size_t)48 << 20));
    _Float16* Vth  = (_Float16*)(base + ((size_t)64 << 20));
    float*    pre  = (float*)(base + ((size_t)80 << 20));
    _Float16* wgt  = (_Float16*)(base + ((size_t)112 << 20));
    const size_t WSZ = 512 * 512;

    cast_h<<<dim3(4096), dim3(256), 0, stream>>>(x, xh, (B * S * E) / 4);
    cast_h<<<dim3(256), dim3(256), 0, stream>>>(Wq, wgt + 0 * WSZ, WSZ / 4);
    cast_h<<<dim3(256), dim3(256), 0, stream>>>(Wk, wgt + 1 * WSZ, WSZ / 4);
    cast_h<<<dim3(256), dim3(256), 0, stream>>>(Wv, wgt + 2 * WSZ, WSZ / 4);
    cast_h<<<dim3(256), dim3(256), 0, stream>>>(Wo, wgt + 3 * WSZ, WSZ / 4);
    cast_h<<<dim3(256), dim3(256), 0, stream>>>(Wih, wgt + 4 * WSZ, WSZ / 4);
    cast_h<<<dim3(256), dim3(256), 0, stream>>>(Wih + WSZ, wgt + 5 * WSZ, WSZ / 4);
    cast_h<<<dim3(256), dim3(256), 0, stream>>>(Whh, wgt + 6 * WSZ, WSZ / 4);
    cast_h<<<dim3(256), dim3(256), 0, stream>>>(Whh + WSZ, wgt + 7 * WSZ, WSZ / 4);

    const dim3 gg(4, 128), blk(256);
    gemm_mfma<1><<<gg, blk, 0, stream>>>(xh, wgt + 0 * WSZ, bq, Qh, B * S, E, E);
    gemm_mfma<1><<<gg, blk, 0, stream>>>(xh, wgt + 1 * WSZ, bk, Kh, B * S, E, E);
    gemm_mfma<2><<<gg, blk, 0, stream>>>(xh, wgt + 2 * WSZ, bv, Vth, B * S, E, E);
    attn_mfma<<<dim3(B * NH * 8), blk, 0, stream>>>(Qh, Kh, Vth);
    gemm_mfma<1><<<gg, blk, 0, stream>>>(Qh, wgt + 3 * WSZ, bo, Kh, B * S, E, E);
    gemm_mfma<3><<<gg, blk, 0, stream>>>(Kh, wgt + 4 * WSZ, bih, pre, B * S, H, E);

    // poison both h slabs, then the fused 2-layer RNN (512 blocks, round-12 step)
    fill_poison<<<dim3(1024), blk, 0, stream>>>((uint4*)base, (32 << 20) / 16);
    fill_poison<<<dim3(1024), blk, 0, stream>>>((uint4*)(base + ((size_t)48 << 20)),
                                                (32 << 20) / 16);
    rnn_fused2L<<<dim3(512), blk, 0, stream>>>(pre, wgt + 6 * WSZ, wgt + 7 * WSZ,
                                               wgt + 5 * WSZ, bhh, bih, h0u, h1u);
    fc_out<<<dim3(32), dim3(64), 0, stream>>>(h1u + (size_t)511 * B * H, Wfc, bfc, out);
}

// Round 20
// 1222.105 us; speedup vs baseline: 1.5651x; 1.5651x over previous
//
#include <hip/hip_runtime.h>
#include <hip/hip_fp16.h>

#define B 32
#define S 512
#define E 512
#define H 512
#define NH 8
#define HD 64
#define POISON 0x7FC0DEADu

typedef _Float16 h16x8 __attribute__((ext_vector_type(8)));
typedef _Float16 h16x4 __attribute__((ext_vector_type(4)));
typedef _Float16 h16x2 __attribute__((ext_vector_type(2)));
typedef float f32x4 __attribute__((ext_vector_type(4)));

#if __has_builtin(__builtin_amdgcn_fdot2)
__device__ __forceinline__ float dot2f(h16x2 a, h16x2 b, float c) {
    return __builtin_amdgcn_fdot2(a, b, c, false);
}
#else
__device__ __forceinline__ float dot2f(h16x2 a, h16x2 b, float c) {
    return c + (float)a[0] * (float)b[0] + (float)a[1] * (float)b[1];
}
#endif

__device__ __forceinline__ h16x2 pr(h16x8 v, int q) {
    h16x2 r; r[0] = v[2 * q]; r[1] = v[2 * q + 1]; return r;
}

// ---------------- fp32 -> fp16 cast (vectorized, grid-stride) ----------------
__global__ __launch_bounds__(256) void cast_h(const float* __restrict__ src,
                                              _Float16* __restrict__ dst, int n4) {
    int i = blockIdx.x * 256 + threadIdx.x;
    const int stride = gridDim.x * 256;
    for (; i < n4; i += stride) {
        float4 v = ((const float4*)src)[i];
        h16x4 o;
        o[0] = (_Float16)v.x; o[1] = (_Float16)v.y;
        o[2] = (_Float16)v.z; o[3] = (_Float16)v.w;
        ((h16x4*)dst)[i] = o;
    }
}

// ---------------- MFMA GEMM: C[M,N] = A[M,K] @ W[N,K]^T + bias ----------------
// OMODE 0: f32 row-major. 1: f16 row-major. 2: f16 scattered to Vt[(b*8+h)*64+d][s].
// 3: f32 time-major scatter row r=b*512+s -> C[(s*32+b)*N+c].
template <int OMODE>
__global__ __launch_bounds__(256) void gemm_mfma(const _Float16* __restrict__ A,
                                                 const _Float16* __restrict__ W,
                                                 const float* __restrict__ bias,
                                                 void* __restrict__ Cout,
                                                 int M, int N, int K) {
    __shared__ __align__(16) _Float16 Als[128 * 32];
    __shared__ __align__(16) _Float16 Bls[128 * 32];
    const int tid = threadIdx.x;
    const int m0 = blockIdx.y * 128;
    const int n0 = blockIdx.x * 128;
    const int lane = tid & 63;
    const int w = tid >> 6;
    const int wm = w >> 1, wn = w & 1;
    f32x4 acc[4][4] = {};

    const int srow = tid >> 1;
    const int shalf = tid & 1;
    const _Float16* Ag = A + (size_t)(m0 + srow) * K + shalf * 16;
    const _Float16* Wg = W + (size_t)(n0 + srow) * K + shalf * 16;

    for (int k0 = 0; k0 < K; k0 += 32) {
        h16x8 a0 = *(const h16x8*)(Ag + k0);
        h16x8 a1 = *(const h16x8*)(Ag + k0 + 8);
        h16x8 b0 = *(const h16x8*)(Wg + k0);
        h16x8 b1 = *(const h16x8*)(Wg + k0 + 8);
        __syncthreads();
        *(h16x8*)&Als[srow * 32 + shalf * 16] = a0;
        *(h16x8*)&Als[srow * 32 + shalf * 16 + 8] = a1;
        *(h16x8*)&Bls[srow * 32 + shalf * 16] = b0;
        *(h16x8*)&Bls[srow * 32 + shalf * 16 + 8] = b1;
        __syncthreads();
        h16x8 af[4], bf[4];
#pragma unroll
        for (int mt = 0; mt < 4; ++mt)
            af[mt] = *(const h16x8*)&Als[(wm * 64 + mt * 16 + (lane & 15)) * 32 + (lane >> 4) * 8];
#pragma unroll
        for (int nt = 0; nt < 4; ++nt)
            bf[nt] = *(const h16x8*)&Bls[(wn * 64 + nt * 16 + (lane & 15)) * 32 + (lane >> 4) * 8];
#pragma unroll
        for (int mt = 0; mt < 4; ++mt)
#pragma unroll
            for (int nt = 0; nt < 4; ++nt)
                acc[mt][nt] = __builtin_amdgcn_mfma_f32_16x16x32_f16(af[mt], bf[nt], acc[mt][nt], 0, 0, 0);
    }

    float* Cf = (float*)Cout;
    _Float16* Ch = (_Float16*)Cout;
    const int colb = n0 + wn * 64 + (lane & 15);
    const int rowb = m0 + wm * 64 + ((lane >> 4) << 2);
#pragma unroll
    for (int mt = 0; mt < 4; ++mt) {
#pragma unroll
        for (int nt = 0; nt < 4; ++nt) {
            const int c = colb + nt * 16;
            const float bv = bias[c];
            if (OMODE == 2) {
                const int R0 = rowb + mt * 16;
                const int bb = R0 >> 9, s = R0 & 511, hh = c >> 6, d = c & 63;
                h16x4 pk;
#pragma unroll
                for (int j = 0; j < 4; ++j) pk[j] = (_Float16)(acc[mt][nt][j] + bv);
                *(h16x4*)&Ch[((size_t)(bb * 8 + hh) * 64 + d) * 512 + s] = pk;
            } else {
#pragma unroll
                for (int j = 0; j < 4; ++j) {
                    const int R = rowb + mt * 16 + j;
                    const float v = acc[mt][nt][j] + bv;
                    if (OMODE == 0) Cf[(size_t)R * N + c] = v;
                    else if (OMODE == 3) Cf[((size_t)(R & 511) * 32 + (R >> 9)) * N + c] = v;
                    else Ch[(size_t)R * N + c] = (_Float16)v;
                }
            }
        }
    }
}

// ---------------- MFMA flash attention: per (b, h, 64-row q-tile) ----------------
__global__ __launch_bounds__(256) void attn_mfma(_Float16* __restrict__ Qb,
                                                 const _Float16* __restrict__ Kb,
                                                 const _Float16* __restrict__ Vt) {
    __shared__ __align__(16) _Float16 Qs[64 * 72];
    __shared__ __align__(16) _Float16 Ks[64 * 72];
    __shared__ __align__(16) _Float16 Vs[64 * 72];
    __shared__ __align__(16) _Float16 Ps[4 * 16 * 72];
    const int tid = threadIdx.x;
    const int lane = tid & 63;
    const int w = tid >> 6;
    const int qt = blockIdx.x & 7;
    const int h = (blockIdx.x >> 3) & 7;
    const int b = blockIdx.x >> 6;
    const size_t qrow0 = (size_t)b * 512 + qt * 64;
    const int col0 = h * 64;

    {
        const int r = tid >> 2;
        const int c0 = (tid & 3) << 4;
        const _Float16* gq = &Qb[(qrow0 + r) * 512 + col0 + c0];
        *(h16x8*)&Qs[r * 72 + c0] = *(const h16x8*)(gq);
        *(h16x8*)&Qs[r * 72 + c0 + 8] = *(const h16x8*)(gq + 8);
    }
    __syncthreads();
    h16x8 aq[2];
#pragma unroll
    for (int ks = 0; ks < 2; ++ks)
        aq[ks] = *(const h16x8*)&Qs[(w * 16 + (lane & 15)) * 72 + ks * 32 + (lane >> 4) * 8];

    float m[4] = {-1e30f, -1e30f, -1e30f, -1e30f};
    float l[4] = {0.f, 0.f, 0.f, 0.f};
    f32x4 acco[4] = {};

    for (int kt = 0; kt < 8; ++kt) {
        __syncthreads();
        {
            const int r = tid >> 2;
            const int c0 = (tid & 3) << 4;
            const _Float16* gk = &Kb[((size_t)b * 512 + kt * 64 + r) * 512 + col0 + c0];
            *(h16x8*)&Ks[r * 72 + c0] = *(const h16x8*)(gk);
            *(h16x8*)&Ks[r * 72 + c0 + 8] = *(const h16x8*)(gk + 8);
            const _Float16* gv = &Vt[((size_t)(b * 8 + h) * 64 + r) * 512 + kt * 64 + c0];
            *(h16x8*)&Vs[r * 72 + c0] = *(const h16x8*)(gv);
            *(h16x8*)&Vs[r * 72 + c0 + 8] = *(const h16x8*)(gv + 8);
        }
        __syncthreads();
        f32x4 accs[4] = {};
#pragma unroll
        for (int nt = 0; nt < 4; ++nt) {
#pragma unroll
            for (int ks = 0; ks < 2; ++ks) {
                h16x8 bk = *(const h16x8*)&Ks[(nt * 16 + (lane & 15)) * 72 + ks * 32 + (lane >> 4) * 8];
                accs[nt] = __builtin_amdgcn_mfma_f32_16x16x32_f16(aq[ks], bk, accs[nt], 0, 0, 0);
            }
        }
#pragma unroll
        for (int j = 0; j < 4; ++j) {
            float v = fmaxf(fmaxf(accs[0][j], accs[1][j]), fmaxf(accs[2][j], accs[3][j]));
#pragma unroll
            for (int o = 1; o < 16; o <<= 1) v = fmaxf(v, __shfl_xor(v, o, 64));
            const float mn = fmaxf(m[j], v);
            const float scl = __expf(0.125f * (m[j] - mn));
            m[j] = mn;
            l[j] *= scl;
#pragma unroll
            for (int nt2 = 0; nt2 < 4; ++nt2) acco[nt2][j] *= scl;
            float ps = 0.f;
            const int prow = ((lane >> 4) << 2) + j;
#pragma unroll
            for (int nt = 0; nt < 4; ++nt) {
                const float p = __expf(0.125f * (accs[nt][j] - mn));
                ps += p;
                Ps[w * 16 * 72 + prow * 72 + nt * 16 + (lane & 15)] = (_Float16)p;
            }
#pragma unroll
            for (int o = 1; o < 16; o <<= 1) ps += __shfl_xor(ps, o, 64);
            l[j] += ps;
        }
        __syncthreads();
#pragma unroll
        for (int ks2 = 0; ks2 < 2; ++ks2) {
            h16x8 pa = *(const h16x8*)&Ps[w * 16 * 72 + (lane & 15) * 72 + ks2 * 32 + (lane >> 4) * 8];
#pragma unroll
            for (int nt2 = 0; nt2 < 4; ++nt2) {
                h16x8 bv = *(const h16x8*)&Vs[(nt2 * 16 + (lane & 15)) * 72 + ks2 * 32 + (lane >> 4) * 8];
                acco[nt2] = __builtin_amdgcn_mfma_f32_16x16x32_f16(pa, bv, acco[nt2], 0, 0, 0);
            }
        }
    }
#pragma unroll
    for (int j = 0; j < 4; ++j) {
        const float inv = 1.0f / l[j];
        const size_t r = qrow0 + w * 16 + ((lane >> 4) << 2) + j;
#pragma unroll
        for (int nt2 = 0; nt2 < 4; ++nt2)
            Qb[r * 512 + col0 + nt2 * 16 + (lane & 15)] = (_Float16)(acco[nt2][j] * inv);
    }
}

// ---------------- poison fill ----------------
__global__ __launch_bounds__(256) void fill_poison(uint4* __restrict__ p, int n) {
    const uint4 v = {POISON, POISON, POISON, POISON};
    int i = blockIdx.x * 256 + threadIdx.x;
    const int st = gridDim.x * 256;
    for (; i < n; i += st) p[i] = v;
}

__device__ __forceinline__ unsigned long long poll2(const unsigned* p) {
    unsigned long long v = __hip_atomic_load((const unsigned long long*)p,
                                             __ATOMIC_RELAXED, __HIP_MEMORY_SCOPE_AGENT);
    while ((unsigned)v == POISON || (unsigned)(v >> 32) == POISON) {
        __builtin_amdgcn_s_sleep(1);
        v = __hip_atomic_load((const unsigned long long*)p,
                              __ATOMIC_RELAXED, __HIP_MEMORY_SCOPE_AGENT);
    }
    return v;
}

// ---------------- persistent single-layer RNN (256 blocks = 32 b x 8 slices) --------
// Round-12 structure (verified best): fp16 weights streamed from L2 with loads issued
// before the poll; per-thread u64 poison-poll dataflow; part[][] LDS reduce.
__global__ __launch_bounds__(256) void rnn_persist(const float* __restrict__ pre,
                                                   const _Float16* __restrict__ W16,
                                                   const float* __restrict__ bhh,
                                                   unsigned* __restrict__ hbuf,
                                                   _Float16* __restrict__ hbuf_h) {
    __shared__ float hl[512];
    __shared__ float part[64][17];
    const int tid = threadIdx.x;
    const int b = blockIdx.x & 31;
    const int sl = blockIdx.x >> 5;
    const int jq = tid & 15, kg = tid >> 4;
    const int jbase = sl * 64, k0 = kg * 32;
    const int j64 = tid & 63;

    const _Float16* w0p = W16 + (size_t)(jbase + jq * 4 + 0) * 512 + k0;
    const _Float16* w1p = W16 + (size_t)(jbase + jq * 4 + 1) * 512 + k0;
    const _Float16* w2p = W16 + (size_t)(jbase + jq * 4 + 2) * 512 + k0;
    const _Float16* w3p = W16 + (size_t)(jbase + jq * 4 + 3) * 512 + k0;
    const float bj = bhh[jbase + j64];

    for (int t = 0; t < S; ++t) {
        // issue weight + pre loads first so they fly during the poll spin
        h16x8 w0[4], w1[4], w2[4], w3[4];
#pragma unroll
        for (int c8 = 0; c8 < 4; ++c8) {
            w0[c8] = *(const h16x8*)(w0p + c8 * 8);
            w1[c8] = *(const h16x8*)(w1p + c8 * 8);
            w2[c8] = *(const h16x8*)(w2p + c8 * 8);
            w3[c8] = *(const h16x8*)(w3p + c8 * 8);
        }
        const float pv = pre[((size_t)t * 32 + b) * 512 + jbase + j64];
        float a0 = 0.f, a1 = 0.f, a2 = 0.f, a3 = 0.f;
        if (t > 0) {
            const unsigned long long v = poll2(hbuf + (size_t)(t - 1) * (B * H) + b * H + tid * 2);
            hl[tid * 2] = __uint_as_float((unsigned)v);
            hl[tid * 2 + 1] = __uint_as_float((unsigned)(v >> 32));
            __syncthreads();
            f32x4 hw[8];
#pragma unroll
            for (int c = 0; c < 8; ++c) hw[c] = *(const f32x4*)&hl[k0 + c * 4];
            h16x2 hp[16];
#pragma unroll
            for (int c = 0; c < 8; ++c) {
                h16x2 p0, p1;
                p0[0] = (_Float16)hw[c][0]; p0[1] = (_Float16)hw[c][1];
                p1[0] = (_Float16)hw[c][2]; p1[1] = (_Float16)hw[c][3];
                hp[2 * c] = p0; hp[2 * c + 1] = p1;
            }
#pragma unroll
            for (int c8 = 0; c8 < 4; ++c8) {
#pragma unroll
                for (int q = 0; q < 4; ++q) {
                    a0 = dot2f(pr(w0[c8], q), hp[c8 * 4 + q], a0);
                    a1 = dot2f(pr(w1[c8], q), hp[c8 * 4 + q], a1);
                    a2 = dot2f(pr(w2[c8], q), hp[c8 * 4 + q], a2);
                    a3 = dot2f(pr(w3[c8], q), hp[c8 * 4 + q], a3);
                }
            }
        }
        part[jq * 4 + 0][kg] = a0;
        part[jq * 4 + 1][kg] = a1;
        part[jq * 4 + 2][kg] = a2;
        part[jq * 4 + 3][kg] = a3;
        __syncthreads();   // also: hl fully consumed
        if (tid < 64) {
            float s2 = 0.f;
#pragma unroll
            for (int i = 0; i < 16; ++i) s2 += part[tid][i];
            s2 += bj + pv;
            s2 = fminf(fmaxf(s2, -15.f), 15.f);
            const float ex = __expf(2.f * s2);
            const float hval = (ex - 1.f) / (ex + 1.f);
            const size_t idx = (size_t)t * (B * H) + b * H + jbase + tid;
            __hip_atomic_store(&hbuf[idx], __float_as_uint(hval),
                               __ATOMIC_RELAXED, __HIP_MEMORY_SCOPE_AGENT);
            hbuf_h[idx] = (_Float16)hval;
        }
        __syncthreads();   // part[] + hl protected before next iteration
    }
}

// ---------------- final FC: out[b] = h1[511][b,:] . Wfc[0,:] + bfc[0] ----------------
__global__ __launch_bounds__(64) void fc_out(const unsigned* __restrict__ hbits,
                                             const float* __restrict__ Wfc,
                                             const float* __restrict__ bfc,
                                             float* __restrict__ out) {
    int b = blockIdx.x;
    int t = threadIdx.x;
    float a = 0.f;
    for (int j = t; j < 512; j += 64) a += __uint_as_float(hbits[b * 512 + j]) * Wfc[j];
#pragma unroll
    for (int o = 32; o; o >>= 1) a += __shfl_down(a, o, 64);
    if (t == 0) out[b] = a + bfc[0];
}

extern "C" void kernel_launch(void* const* d_in, const int* in_sizes, int n_in,
                              void* d_out, int out_size, void* d_ws, size_t ws_size,
                              hipStream_t stream) {
    const float* x   = (const float*)d_in[0];
    const float* Wq  = (const float*)d_in[1];
    const float* bq  = (const float*)d_in[2];
    const float* Wk  = (const float*)d_in[3];
    const float* bk  = (const float*)d_in[4];
    const float* Wv  = (const float*)d_in[5];
    const float* bv  = (const float*)d_in[6];
    const float* Wo  = (const float*)d_in[7];
    const float* bo  = (const float*)d_in[8];
    const float* Wih = (const float*)d_in[9];
    const float* bih = (const float*)d_in[10];
    const float* Whh = (const float*)d_in[11];
    const float* bhh = (const float*)d_in[12];
    const float* Wfc = (const float*)d_in[13];
    const float* bfc = (const float*)d_in[14];
    float* out = (float*)d_out;
    char* base = (char*)d_ws;

    _Float16* xh   = (_Float16*)(base);
    unsigned* h0u  = (unsigned*)(base);
    _Float16* Qh   = (_Float16*)(base + ((size_t)32 << 20));
    _Float16* h0h  = (_Float16*)(base + ((size_t)32 << 20));
    _Float16* Kh   = (_Float16*)(base + ((size_t)48 << 20));
    unsigned* h1u  = (unsigned*)(base + ((size_t)48 << 20));
    _Float16* Vth  = (_Float16*)(base + ((size_t)64 << 20));
    float*    pre  = (float*)(base + ((size_t)80 << 20));
    _Float16* wgt  = (_Float16*)(base + ((size_t)112 << 20));
    const size_t WSZ = 512 * 512;

    cast_h<<<dim3(4096), dim3(256), 0, stream>>>(x, xh, (B * S * E) / 4);
    cast_h<<<dim3(256), dim3(256), 0, stream>>>(Wq, wgt + 0 * WSZ, WSZ / 4);
    cast_h<<<dim3(256), dim3(256), 0, stream>>>(Wk, wgt + 1 * WSZ, WSZ / 4);
    cast_h<<<dim3(256), dim3(256), 0, stream>>>(Wv, wgt + 2 * WSZ, WSZ / 4);
    cast_h<<<dim3(256), dim3(256), 0, stream>>>(Wo, wgt + 3 * WSZ, WSZ / 4);
    cast_h<<<dim3(256), dim3(256), 0, stream>>>(Wih, wgt + 4 * WSZ, WSZ / 4);
    cast_h<<<dim3(256), dim3(256), 0, stream>>>(Wih + WSZ, wgt + 5 * WSZ, WSZ / 4);
    cast_h<<<dim3(256), dim3(256), 0, stream>>>(Whh, wgt + 6 * WSZ, WSZ / 4);
    cast_h<<<dim3(256), dim3(256), 0, stream>>>(Whh + WSZ, wgt + 7 * WSZ, WSZ / 4);

    const dim3 gg(4, 128), blk(256);
    gemm_mfma<1><<<gg, blk, 0, stream>>>(xh, wgt + 0 * WSZ, bq, Qh, B * S, E, E);
    gemm_mfma<1><<<gg, blk, 0, stream>>>(xh, wgt + 1 * WSZ, bk, Kh, B * S, E, E);
    gemm_mfma<2><<<gg, blk, 0, stream>>>(xh, wgt + 2 * WSZ, bv, Vth, B * S, E, E);
    attn_mfma<<<dim3(B * NH * 8), blk, 0, stream>>>(Qh, Kh, Vth);
    gemm_mfma<1><<<gg, blk, 0, stream>>>(Qh, wgt + 3 * WSZ, bo, Kh, B * S, E, E);
    gemm_mfma<3><<<gg, blk, 0, stream>>>(Kh, wgt + 4 * WSZ, bih, pre, B * S, H, E);

    fill_poison<<<dim3(1024), blk, 0, stream>>>((uint4*)base, (32 << 20) / 16);
    rnn_persist<<<dim3(256), blk, 0, stream>>>(pre, wgt + 6 * WSZ, bhh, h0u, h0h);
    gemm_mfma<0><<<gg, blk, 0, stream>>>(h0h, wgt + 5 * WSZ, bih + 512, pre, B * S, H, H);
    fill_poison<<<dim3(1024), blk, 0, stream>>>((uint4*)(base + ((size_t)48 << 20)),
                                                (32 << 20) / 16);
    rnn_persist<<<dim3(256), blk, 0, stream>>>(pre, wgt + 7 * WSZ, bhh + 512, h1u, h0h);
    fc_out<<<dim3(32), dim3(64), 0, stream>>>(h1u + (size_t)511 * B * H, Wfc, bfc, out);
}